// Round 3
// baseline (445.530 us; speedup 1.0000x reference)
//
#include <hip/hip_runtime.h>

// Problem: B,C,H,W = 16,256,32,32; K=16384. N = 16384 rows.
// R13: R2 post-mortem: k2 no longer LLC-BW bound (7.7 TB/s < 11 demonstrated) -- the
//      per-step issue-early/drain-at-end schedule exposes ~500 cyc of staging latency
//      every step (loads issued at step top, vmcnt(0)-drained at step bottom).
//      Fix: (1) 128-row tiles / 512 threads (traffic 2.15 -> 1.07 GB, per-CU step
//      count halves; wave tile stays the proven 64x64); (2) 3-deep Bs ring with
//      counted vmcnt(2) + raw s_barrier per step (T3/T4): loads get a 2-step
//      (~2000 cyc) latency budget, no vmcnt(0) drain in the steady-state loop.
//      Safety: buf(s+2)%3 == buf(s-1)%3 and the step-s barrier orders all waves past
//      step s-1's reads before the new issue; exactly 2 global_load_lds/wave/step so
//      vmcnt(2) == "my step-s loads done"; s==255 uses vmcnt(0); fold's wn loads are
//      drained by the fold's own __syncthreads. asm("":::"memory")+sched_barrier(0)
//      fence IR/MIR motion around the raw barrier (rule #18).
#define KCODES 16384
#define NPOS   16384
#define KHALF  8192
#define CAPH   64      // per-half candidate cap (R10: 4 rows overflowed at 16; 64/half is ~P(0))
#define MARGIN 1e-4f   // ~100x the single-plane bf16 dot error (sigma ~1e-6 on d)

// ws float offsets (all within the 52.7MB footprint proven in R0)
#define OFF_XT    0           // [N][256] fp32 packed x ("flat")
#define OFF_XHP   4194304     // bf16 plane xh [N][256]
#define OFF_PART  6291456     // [4096][2] k5 per-block {mask,err} partials
#define OFF_CAND  6815744     // u16 [N][2][CAPH] candidate codes (1M floats)
#define OFF_WHP   8388608     // bf16 plane wh [K][256]
#define OFF_WN    12582912    // [K]  |w|^2 (np-pairwise exact)
#define OFF_NS1   12599296    // [N] -|f|^2
#define OFF_IDX   12615680    // [N] final argmax (int)
#define OFF_CCNT  12632064    // int [N][2] candidate counts

#define OUT_LOSS  4194304
#define OUT_IND   4194305

#define AS1 __attribute__((address_space(1)))
#define AS3 __attribute__((address_space(3)))

typedef short bf16x8 __attribute__((ext_vector_type(8)));   // 8 bf16 = 4 VGPRs
typedef float f32x4  __attribute__((ext_vector_type(4)));

__device__ inline unsigned short bf16rn(float f) {
    unsigned u = __float_as_uint(f);
    return (unsigned short)((u + 0x7FFFu + ((u >> 16) & 1u)) >> 16);
}
__device__ inline float bf2f(unsigned short h) {
    return __uint_as_float(((unsigned)h) << 16);
}
__device__ inline unsigned monof(float f) {   // monotone float->uint key
    unsigned u = __float_as_uint(f);
    return (u & 0x80000000u) ? ~u : (u | 0x80000000u);
}
__device__ inline float unmonof(unsigned k) {
    unsigned u = (k & 0x80000000u) ? (k & 0x7fffffffu) : ~k;
    return __uint_as_float(u);
}

// ---------- K1a: pack x (B,C,HW) -> xt[N][256] fp32 + xh bf16, LDS transpose ----
__global__ void k1a_pack_x(const float* __restrict__ x, float* __restrict__ xt,
                           unsigned short* __restrict__ xhp)
{
    __shared__ float t[32][33];
    const int p0 = blockIdx.x * 32, c0 = blockIdx.y * 32, b = blockIdx.z;
    const int tx = threadIdx.x, ty = threadIdx.y;   // 32 x 8
#pragma unroll
    for (int i = 0; i < 4; ++i) {
        int cl = ty + i * 8;
        t[cl][tx] = x[(b * 256 + c0 + cl) * 1024 + p0 + tx];
    }
    __syncthreads();
#pragma unroll
    for (int i = 0; i < 4; ++i) {
        int pl = ty + i * 8;
        float v = t[tx][pl];
        int o = (b * 1024 + p0 + pl) * 256 + c0 + tx;
        xt[o] = v;
        xhp[o] = bf16rn(v);
    }
}

// ---------- Krn: numpy-pairwise fp32 sum of squares per 256-elem row ----------
__global__ void k_rownorm(const float4* __restrict__ src4, float* __restrict__ out,
                          float sign, ushort4* __restrict__ hp)
{
    __shared__ float4 rows[32 * 64];
    const int tid = threadIdx.x;
    const int r0 = blockIdx.x * 32;
#pragma unroll
    for (int i = 0; i < 8; ++i) {
        const float4 v = src4[r0 * 64 + tid + 256 * i];
        rows[tid + 256 * i] = v;
        if (hp) {
            ushort4 h;
            h.x = bf16rn(v.x); h.y = bf16rn(v.y);
            h.z = bf16rn(v.z); h.w = bf16rn(v.w);
            hp[r0 * 64 + tid + 256 * i] = h;
        }
    }
    __syncthreads();
    const int rl = tid >> 3, j = tid & 7;
    const float* qp = (const float*)&rows[rl * 64];
    float h[2];
#pragma unroll
    for (int half = 0; half < 2; ++half) {
        const float* p = qp + half * 128;
        float x = p[j];
        float r = __fmul_rn(x, x);
#pragma unroll
        for (int i = 1; i < 16; ++i) {
            float y = p[8 * i + j];
            r = __fadd_rn(r, __fmul_rn(y, y));
        }
        float t = __fadd_rn(r, __shfl_xor(r, 1));
        t = __fadd_rn(t, __shfl_xor(t, 2));
        t = __fadd_rn(t, __shfl_xor(t, 4));
        h[half] = t;
    }
    if (j == 0) out[r0 + rl] = sign * __fadd_rn(h[0], h[1]);
}

// ---------- K2: 128-row x K-half bf16 MFMA, 3-deep counted-vmcnt pipeline ------
// d_approx = 2*(xh.wh) - |w|^2 (per-row -|f|^2 constant omitted: argmax-invariant).
// Block = (rowGroup = bid>>1) x (K-half = bid&1). 256 blocks = 1/CU.
__global__ __launch_bounds__(512, 2) void k2_mfma(
    const unsigned short* __restrict__ xhp, const unsigned short* __restrict__ whp,
    const float* __restrict__ wn,
    unsigned short* __restrict__ candk, int* __restrict__ candc)
{
    __shared__ __align__(16) unsigned short As[32768];     // 64KB: slot16 = cc*128 + row
    __shared__ __align__(16) unsigned short Bs[3][8192];   // 3x16KB ring: slot16 = code*4 + q'
    __shared__ unsigned rowmaxU[128];
    __shared__ int ccnt[128];
    __shared__ unsigned short ck[128][CAPH];               // 16 KB

    const int tid  = threadIdx.x;
    const int lane = tid & 63;
    const int w    = tid >> 6;     // wave 0..7
    const int wx   = w & 3;        // code quarter (64 codes)
    const int wy   = w >> 2;       // row half (64 rows)
    const int q    = lane >> 4;    // k-chunk quad
    const int nn   = lane & 15;    // A-row / B-col / D-col position
    const int half = blockIdx.x & 1;
    const int rowBase = (blockIdx.x >> 1) * 128;
    const unsigned short* whpH = whp + half * (KHALF * 256);
    const float* wnH = wn + half * KHALF;

    // prologue: stage As (4096 slots of 16B = 128 rows x 256 ch bf16)
#pragma unroll
    for (int i = 0; i < 8; ++i) {
        const int slot = i * 512 + tid;
        const int cc = slot >> 7, row = slot & 127;
        const unsigned short* src = xhp + (rowBase + row) * 256 + cc * 8;
        __builtin_amdgcn_global_load_lds((const AS1 void*)src,
                                         (AS3 void*)((char*)&As[0] + slot * 16), 16, 0, 0);
    }
    // prologue: stage Bs[0] (step 0) and Bs[1] (step 1)
#pragma unroll
    for (int sp = 0; sp < 2; ++sp)
#pragma unroll
        for (int i = 0; i < 2; ++i) {
            const int slot = i * 512 + tid;
            const int code = slot >> 2;
            const int qq = (slot & 3) ^ ((code >> 1) & 3);     // bank swizzle
            const unsigned short* src = whpH + code * 256 + sp * 32 + qq * 8;
            __builtin_amdgcn_global_load_lds((const AS1 void*)src,
                (AS3 void*)((char*)&Bs[sp][0] + slot * 16), 16, 0, 0);
        }
    if (tid < 128) { rowmaxU[tid] = 0u; ccnt[tid] = 0; }
    __syncthreads();           // full drain: As + Bs[0] + Bs[1] ready, all waves synced

    int rbuf = 0;              // ring index of the buffer holding step s
    for (int ch = 0; ch < 32; ++ch) {
        const int kb = ch * 256;
        f32x4 acc[4][4];
#pragma unroll
        for (int rt = 0; rt < 4; ++rt)
#pragma unroll
            for (int ct = 0; ct < 4; ++ct) acc[rt][ct] = (f32x4){0.f, 0.f, 0.f, 0.f};

        for (int cs = 0; cs < 8; ++cs) {
            const int s = ch * 8 + cs;
            // [1] my loads for step s complete (2 newest in flight are step s+1's)
            if (s >= 2) {
                if (s < 255) { asm volatile("s_waitcnt vmcnt(2)" ::: "memory"); }
                else         { asm volatile("s_waitcnt vmcnt(0)" ::: "memory"); }
                __builtin_amdgcn_sched_barrier(0);
            }
            // [2] everyone's step-s loads done; everyone's step-(s-1) reads done
            __builtin_amdgcn_s_barrier();
            asm volatile("" ::: "memory");           // IR-level fence (no instr)
            __builtin_amdgcn_sched_barrier(0);
            // [3] issue step s+2 into buf (rbuf+2)%3 == buf (s-1)%3 (safe per [2])
            if (s + 2 < 256) {
                const int sn = s + 2;
                const int nch = sn >> 3, ncs = sn & 7;
                const int wbuf = (rbuf + 2 >= 3) ? (rbuf - 1) : (rbuf + 2);
#pragma unroll
                for (int i = 0; i < 2; ++i) {
                    const int slot = i * 512 + tid;
                    const int code = slot >> 2;
                    const int qq = (slot & 3) ^ ((code >> 1) & 3);
                    const unsigned short* src = whpH + (nch * 256 + code) * 256 + ncs * 32 + qq * 8;
                    __builtin_amdgcn_global_load_lds((const AS1 void*)src,
                        (AS3 void*)((char*)&Bs[wbuf][0] + slot * 16), 16, 0, 0);
                }
            }
            // [4] compute step s from Bs[rbuf]
            bf16x8 bh[4];
#pragma unroll
            for (int ct = 0; ct < 4; ++ct) {
                const int codeL = wx * 64 + ct * 16 + nn;
                const int qp = q ^ ((codeL >> 1) & 3);
                bh[ct] = *(const bf16x8*)&Bs[rbuf][(codeL * 4 + qp) * 8];
            }
#pragma unroll
            for (int rt = 0; rt < 4; ++rt) {
                const int as = (cs * 4 + q) * 128 + wy * 64 + rt * 16 + nn;
                const bf16x8 ah = *(const bf16x8*)&As[as * 8];
#pragma unroll
                for (int ct = 0; ct < 4; ++ct)
                    acc[rt][ct] = __builtin_amdgcn_mfma_f32_16x16x32_bf16(ah, bh[ct], acc[rt][ct], 0, 0, 0);
            }
            rbuf = (rbuf + 1 == 3) ? 0 : rbuf + 1;
        }

        // ---- fold: approx d, shared row-max, candidate collection ----
        float wnv[4];
#pragma unroll
        for (int ct = 0; ct < 4; ++ct) wnv[ct] = wnH[kb + wx * 64 + ct * 16 + nn];
        float rmax[16];
#pragma unroll
        for (int r16 = 0; r16 < 16; ++r16) rmax[r16] = -3.0e38f;
#pragma unroll
        for (int rt = 0; rt < 4; ++rt)
#pragma unroll
            for (int ct = 0; ct < 4; ++ct)
#pragma unroll
                for (int rg = 0; rg < 4; ++rg) {
                    const float dv = __builtin_fmaf(2.0f, acc[rt][ct][rg], -wnv[ct]);
                    rmax[rt * 4 + rg] = fmaxf(rmax[rt * 4 + rg], dv);
                }
#pragma unroll
        for (int r16 = 0; r16 < 16; ++r16) {
            float m = rmax[r16];
            m = fmaxf(m, __shfl_xor(m, 1, 64));
            m = fmaxf(m, __shfl_xor(m, 2, 64));
            m = fmaxf(m, __shfl_xor(m, 4, 64));
            m = fmaxf(m, __shfl_xor(m, 8, 64));
            rmax[r16] = m;
        }
        if (nn == 0) {
#pragma unroll
            for (int rt = 0; rt < 4; ++rt)
#pragma unroll
                for (int rg = 0; rg < 4; ++rg)
                    atomicMax(&rowmaxU[wy * 64 + rt * 16 + q * 4 + rg],
                              monof(rmax[rt * 4 + rg]));
        }
        __syncthreads();       // rowmax merged (drains fold's wn loads too)
        float th[16];
#pragma unroll
        for (int rt = 0; rt < 4; ++rt)
#pragma unroll
            for (int rg = 0; rg < 4; ++rg)
                th[rt * 4 + rg] = unmonof(rowmaxU[wy * 64 + rt * 16 + q * 4 + rg]) - MARGIN;
#pragma unroll
        for (int rt = 0; rt < 4; ++rt)
#pragma unroll
            for (int ct = 0; ct < 4; ++ct)
#pragma unroll
                for (int rg = 0; rg < 4; ++rg) {
                    const float dv = __builtin_fmaf(2.0f, acc[rt][ct][rg], -wnv[ct]);
                    if (dv >= th[rt * 4 + rg]) {
                        const int row = wy * 64 + rt * 16 + q * 4 + rg;
                        const int pos = atomicAdd(&ccnt[row], 1);
                        if (pos < CAPH)
                            ck[row][pos] = (unsigned short)(half * KHALF + kb + wx * 64 + ct * 16 + nn);
                    }
                }
        // next step's barrier orders collection vs restage
    }
    __syncthreads();
    if (tid < 128) candc[(rowBase + tid) * 2 + half] = ccnt[tid];
#pragma unroll
    for (int i = 0; i < 16; ++i) {
        const int e = i * 512 + tid;    // 8192 entries = 128 rows x CAPH(64)
        candk[((rowBase + (e >> 6)) * 2 + half) * CAPH + (e & 63)] = ck[e >> 6][e & 63];
    }
}

// ---------- K3: exact rescore — merge both K-halves' candidate lists ----------
__global__ __launch_bounds__(256) void k3_rescore(
    const float* __restrict__ xt, const float* __restrict__ weight,
    const float* __restrict__ wn, const float* __restrict__ ns1,
    const unsigned short* __restrict__ candk, const int* __restrict__ candc,
    int* __restrict__ idx)
{
    const int w = threadIdx.x >> 6, lane = threadIdx.x & 63;
    const int waveId = blockIdx.x * 4 + w;        // 0..4095
#pragma unroll
    for (int rr = 0; rr < 4; ++rr) {
        const int n = waveId * 4 + rr;
        const float4 xv = ((const float4*)(xt + n * 256))[lane];
        const float nsv = ns1[n];
        float bestd = -3.0e38f; int bestk = 0x7fffffff;
#pragma unroll
        for (int half = 0; half < 2; ++half) {
            const int cnt = candc[n * 2 + half];
            if (cnt <= CAPH) {
                for (int i = 0; i < cnt; ++i) {
                    const int k = candk[(n * 2 + half) * CAPH + i];
                    const float4 wv = ((const float4*)(weight + k * 256))[lane];
                    float p = __fmul_rn(xv.x, wv.x);
                    p = __builtin_fmaf(xv.y, wv.y, p);
                    p = __builtin_fmaf(xv.z, wv.z, p);
                    p = __builtin_fmaf(xv.w, wv.w, p);
#pragma unroll
                    for (int off = 1; off < 64; off <<= 1) p += __shfl_xor(p, off, 64);
                    const float t1 = __fadd_rn(nsv, -wn[k]);
                    const float dd = __fadd_rn(t1, __fmul_rn(2.0f, p));
                    if (dd > bestd || (dd == bestd && k < bestk)) { bestd = dd; bestk = k; }
                }
            } else {          // overflow fallback: exact scan of this half
                for (int k = half * KHALF; k < (half + 1) * KHALF; ++k) {
                    const float4 wv = ((const float4*)(weight + k * 256))[lane];
                    float p = __fmul_rn(xv.x, wv.x);
                    p = __builtin_fmaf(xv.y, wv.y, p);
                    p = __builtin_fmaf(xv.z, wv.z, p);
                    p = __builtin_fmaf(xv.w, wv.w, p);
#pragma unroll
                    for (int off = 1; off < 64; off <<= 1) p += __shfl_xor(p, off, 64);
                    const float t1 = __fadd_rn(nsv, -wn[k]);
                    const float dd = __fadd_rn(t1, __fmul_rn(2.0f, p));
                    if (dd > bestd || (dd == bestd && k < bestk)) { bestd = dd; bestk = k; }
                }
            }
        }
        if (lane == 0) idx[n] = bestk;
    }
}

// ---------- K5: gather + transpose-tile coalesced store + loss partials -------
__global__ void k5_out(const float* __restrict__ xt, const float* __restrict__ weight,
                       const float* __restrict__ mask, const int* __restrict__ idx,
                       float* __restrict__ out, float* __restrict__ part)
{
    __shared__ float t[32][33];
    __shared__ float red[4][2];
    const int p0 = blockIdx.x * 32, c0 = blockIdx.y * 32, b = blockIdx.z;
    const int tx = threadIdx.x, ty = threadIdx.y;
    float vloc = 0.f, mloc = 0.f;
#pragma unroll
    for (int i = 0; i < 4; ++i) {
        const int pl = ty + i * 8;
        const int n = b * 1024 + p0 + pl;
        const int id = idx[n];
        const float wq = weight[id * 256 + c0 + tx];      // coalesced 128B per row
        const float xv = xt[n * 256 + c0 + tx];           // coalesced
        const float mval = mask[b * 1024 + p0 + pl];      // broadcast
        t[tx][pl] = wq;                                   // t[c-local][p-local]
        const float e = wq - xv;
        vloc += mval * e * e;
        if (blockIdx.y == 0 && tx == 0) {
            mloc += mval;
            out[OUT_IND + n] = (float)id;
        }
    }
    __syncthreads();
#pragma unroll
    for (int i = 0; i < 4; ++i) {
        const int cl = ty + i * 8;
        out[(b * 256 + c0 + cl) * 1024 + p0 + tx] = t[cl][tx];   // coalesced in tx
    }
    const int lin = ty * 32 + tx, lane = lin & 63, w = lin >> 6;
#pragma unroll
    for (int o = 32; o > 0; o >>= 1) {
        vloc += __shfl_down(vloc, o, 64);
        mloc += __shfl_down(mloc, o, 64);
    }
    if (lane == 0) { red[w][0] = mloc; red[w][1] = vloc; }
    __syncthreads();
    if (lin == 0) {
        const int bid = (b * 8 + blockIdx.y) * 32 + blockIdx.x;
        part[bid * 2 + 0] = red[0][0] + red[1][0] + red[2][0] + red[3][0];
        part[bid * 2 + 1] = red[0][1] + red[1][1] + red[2][1] + red[3][1];
    }
}

// ---------- K6: deterministic tree-reduce of 4096 partials + finalize loss ----
__global__ void k6_final(const float* __restrict__ part, float* __restrict__ out)
{
    __shared__ double red[4][2];
    const int tid = threadIdx.x;
    double m = 0.0, s = 0.0;
    for (int i = tid; i < 4096; i += 256) {
        m += (double)part[i * 2 + 0];
        s += (double)part[i * 2 + 1];
    }
    const int lane = tid & 63, w = tid >> 6;
    for (int o = 32; o > 0; o >>= 1) {
        m += __shfl_down(m, o, 64);
        s += __shfl_down(s, o, 64);
    }
    if (lane == 0) { red[w][0] = m; red[w][1] = s; }
    __syncthreads();
    if (tid == 0) {
        const double mt = red[0][0] + red[1][0] + red[2][0] + red[3][0];
        const double st = red[0][1] + red[1][1] + red[2][1] + red[3][1];
        out[OUT_LOSS] = (float)(1.25 * st / (256.0 * mt));
    }
}

extern "C" void kernel_launch(void* const* d_in, const int* in_sizes, int n_in,
                              void* d_out, int out_size, void* d_ws, size_t ws_size,
                              hipStream_t stream)
{
    const float* x      = (const float*)d_in[0];   // [16,256,32,32]
    const float* mask   = (const float*)d_in[1];   // [16,1,32,32]
    const float* weight = (const float*)d_in[2];   // [16384,256]
    float* out = (float*)d_out;
    float* ws  = (float*)d_ws;

    float* xt  = ws + OFF_XT;
    unsigned short* xhp = (unsigned short*)(ws + OFF_XHP);
    unsigned short* whp = (unsigned short*)(ws + OFF_WHP);
    float* wn   = ws + OFF_WN;
    float* ns1  = ws + OFF_NS1;
    int*   idx  = (int*)(ws + OFF_IDX);
    unsigned short* candk = (unsigned short*)(ws + OFF_CAND);
    int*   candc = (int*)(ws + OFF_CCNT);
    float* part = ws + OFF_PART;

    k1a_pack_x<<<dim3(32, 8, 16), dim3(32, 8), 0, stream>>>(x, xt, xhp);
    k_rownorm<<<512, 256, 0, stream>>>((const float4*)xt, ns1, -1.0f, nullptr);
    k_rownorm<<<512, 256, 0, stream>>>((const float4*)weight, wn, 1.0f, (ushort4*)whp);
    k2_mfma<<<256, 512, 0, stream>>>(xhp, whp, wn, candk, candc);
    k3_rescore<<<1024, 256, 0, stream>>>(xt, weight, wn, ns1, candk, candc, idx);
    k5_out<<<dim3(32, 8, 16), dim3(32, 8), 0, stream>>>(xt, weight, mask, idx, out, part);
    k6_final<<<1, 256, 0, stream>>>(part, out);
}

// Round 4
// 387.027 us; speedup vs baseline: 1.1512x; 1.1512x over previous
//
#include <hip/hip_runtime.h>

// Problem: B,C,H,W = 16,256,32,32; K=16384. N = 16384 rows.
// R14: R3 post-mortem: counted-vmcnt ring on a barrier-per-step loop = no gain
//      (~22 cyc/MFMA invariant; the cross-wave staging barrier is the fixed cost).
//      Fix: ELIMINATE B-staging entirely. whp is re-laid-out at pack time into
//      MFMA-fragment order [s][w][ct][nn][q][8] so each lane's bf16x8 B-fragment
//      is a direct 16B global load and each wave streams 4KB/step contiguous.
//      k2's K-loop is barrier-free: per-wave 2-deep register prefetch, compiler
//      per-wave vmcnt, no s_barrier between steps. Only sync left: 1 __syncthreads
//      per fold (every 8 steps). Safe with drifted waves: rowmaxU is a running
//      max that only tightens toward the global max, and MARGIN >= 2*approx-err
//      guarantees the true argmax survives any threshold <= globalMax - 0.
//      Geometry: proven R2 64-row/4-wave/K-half tile, 2 blocks/CU, LDS 41KB.
//      XCD K-half affinity kept (bid&1): each XCD's L2 sees one 4MB half.
#define KCODES 16384
#define NPOS   16384
#define KHALF  8192
#define CAPH   64      // per-half candidate cap (R10: 4 rows overflowed at 16)
#define MARGIN 1e-4f   // ~100x the single-plane bf16 dot error (sigma ~1e-6 on d)

// ws float offsets (all within the 52.7MB footprint proven in R0)
#define OFF_XT    0           // [N][256] fp32 packed x ("flat")
#define OFF_XHP   4194304     // bf16 plane xh [N][256] (linear)
#define OFF_PART  6291456     // [4096][2] k5 per-block {mask,err} partials
#define OFF_CAND  6815744     // u16 [N][2][CAPH] candidate codes (1M floats)
#define OFF_WHP   8388608     // bf16 plane wh, SWIZZLED [half][s][w][ct][nn][q][8]
#define OFF_WN    12582912    // [K]  |w|^2 (np-pairwise exact)
#define OFF_NS1   12599296    // [N] -|f|^2
#define OFF_IDX   12615680    // [N] final argmax (int)
#define OFF_CCNT  12632064    // int [N][2] candidate counts

#define OUT_LOSS  4194304
#define OUT_IND   4194305

#define AS1 __attribute__((address_space(1)))
#define AS3 __attribute__((address_space(3)))

typedef short bf16x8 __attribute__((ext_vector_type(8)));   // 8 bf16 = 4 VGPRs
typedef float f32x4  __attribute__((ext_vector_type(4)));

__device__ inline unsigned short bf16rn(float f) {
    unsigned u = __float_as_uint(f);
    return (unsigned short)((u + 0x7FFFu + ((u >> 16) & 1u)) >> 16);
}
__device__ inline float bf2f(unsigned short h) {
    return __uint_as_float(((unsigned)h) << 16);
}
__device__ inline unsigned monof(float f) {   // monotone float->uint key
    unsigned u = __float_as_uint(f);
    return (u & 0x80000000u) ? ~u : (u | 0x80000000u);
}
__device__ inline float unmonof(unsigned k) {
    unsigned u = (k & 0x80000000u) ? (k & 0x7fffffffu) : ~k;
    return __uint_as_float(u);
}

// ---------- K1a: pack x (B,C,HW) -> xt[N][256] fp32 + xh bf16, LDS transpose ----
__global__ void k1a_pack_x(const float* __restrict__ x, float* __restrict__ xt,
                           unsigned short* __restrict__ xhp)
{
    __shared__ float t[32][33];
    const int p0 = blockIdx.x * 32, c0 = blockIdx.y * 32, b = blockIdx.z;
    const int tx = threadIdx.x, ty = threadIdx.y;   // 32 x 8
#pragma unroll
    for (int i = 0; i < 4; ++i) {
        int cl = ty + i * 8;
        t[cl][tx] = x[(b * 256 + c0 + cl) * 1024 + p0 + tx];
    }
    __syncthreads();
#pragma unroll
    for (int i = 0; i < 4; ++i) {
        int pl = ty + i * 8;
        float v = t[tx][pl];
        int o = (b * 1024 + p0 + pl) * 256 + c0 + tx;
        xt[o] = v;
        xhp[o] = bf16rn(v);
    }
}

// ---------- Krn: numpy-pairwise fp32 row |.|^2; weight path also emits the ------
// ---------- SWIZZLED bf16 plane in k2's fragment order -------------------------
// swizzle: code k -> (half = k>>13; chi = (k&8191)>>8; rem = k&255 -> w,ct,nn),
// channel c -> (cs = c>>5; q = (c&31)>>3; e = c&7).
// short idx = half*2097152 + (chi*8+cs)*8192 + w*2048 + ct*512 + nn*32 + q*8 + e.
__global__ void k_rownorm(const float4* __restrict__ src4, float* __restrict__ out,
                          float sign, unsigned short* __restrict__ hp_swz)
{
    __shared__ float4 rows[32 * 64];
    const int tid = threadIdx.x;
    const int r0 = blockIdx.x * 32;
#pragma unroll
    for (int i = 0; i < 8; ++i) {
        const int F = r0 * 64 + tid + 256 * i;    // float4 index: row = F>>6, c4 = F&63
        const float4 v = src4[F];
        rows[tid + 256 * i] = v;
        if (hp_swz) {
            ushort4 h;
            h.x = bf16rn(v.x); h.y = bf16rn(v.y);
            h.z = bf16rn(v.z); h.w = bf16rn(v.w);
            const int row = F >> 6, c4 = F & 63;
            const int hf = row >> 13, kk = row & 8191;
            const int chi = kk >> 8, rem = kk & 255;
            const int wq = rem >> 6, ct = (rem >> 4) & 3, n4 = rem & 15;
            const int cs = c4 >> 3, qq = (c4 >> 1) & 3, e4 = c4 & 1;
            const int sidx = hf * 2097152 + (chi * 8 + cs) * 8192
                           + wq * 2048 + ct * 512 + n4 * 32 + qq * 8 + e4 * 4;
            *(ushort4*)(hp_swz + sidx) = h;
        }
    }
    __syncthreads();
    const int rl = tid >> 3, j = tid & 7;
    const float* qp = (const float*)&rows[rl * 64];
    float h[2];
#pragma unroll
    for (int half = 0; half < 2; ++half) {
        const float* p = qp + half * 128;
        float x = p[j];
        float r = __fmul_rn(x, x);
#pragma unroll
        for (int i = 1; i < 16; ++i) {
            float y = p[8 * i + j];
            r = __fadd_rn(r, __fmul_rn(y, y));
        }
        float t = __fadd_rn(r, __shfl_xor(r, 1));
        t = __fadd_rn(t, __shfl_xor(t, 2));
        t = __fadd_rn(t, __shfl_xor(t, 4));
        h[half] = t;
    }
    if (j == 0) out[r0 + rl] = sign * __fadd_rn(h[0], h[1]);
}

// ---------- K2: 64-row x K-half, direct-to-reg B loads, barrier-free K-loop ----
// d_approx = 2*(xh.wh) - |w|^2 (per-row -|f|^2 constant omitted: argmax-invariant).
// Block = (rowGroup = bid>>1) x (K-half = bid&1). 512 blocks = 2/CU.
__global__ __launch_bounds__(256, 2) void k2_mfma(
    const unsigned short* __restrict__ xhp, const unsigned short* __restrict__ whp,
    const float* __restrict__ wn,
    unsigned short* __restrict__ candk, int* __restrict__ candc)
{
    __shared__ __align__(16) unsigned short As[16384];     // 32KB: slot16 = cc*64 + row
    __shared__ unsigned rowmaxU[64];
    __shared__ int ccnt[64];
    __shared__ unsigned short ck[64][CAPH];                // 8 KB

    const int tid  = threadIdx.x;
    const int lane = tid & 63;
    const int w    = tid >> 6;     // wave 0..3 -> code sub-range
    const int q    = lane >> 4;    // k-chunk quad
    const int nn   = lane & 15;    // A-row / B-col / D-col position
    const int half = blockIdx.x & 1;
    const int rowBase = (blockIdx.x >> 1) * 64;
    const unsigned short* whpH = whp + half * 2097152;
    const float* wnH = wn + half * KHALF;

    // stage A once: 1024 slots of 16B (64 rows x 256 ch bf16), linear dest
#pragma unroll
    for (int i = 0; i < 8; ++i) {
        const int slot = i * 256 + tid;
        const int cc = slot >> 6, row = slot & 63;
        const unsigned short* src = xhp + (rowBase + row) * 256 + cc * 8;
        __builtin_amdgcn_global_load_lds((const AS1 void*)src,
                                         (AS3 void*)((char*)&As[0] + slot * 16), 16, 0, 0);
    }
    if (tid < 64) { rowmaxU[tid] = 0u; ccnt[tid] = 0; }

    // per-lane fragment pointer into the swizzled codebook plane
    const unsigned short* bptr = whpH + (w * 2048 + nn * 32 + q * 8);

    __syncthreads();           // As staged (drains vmcnt once, prologue only)

    bf16x8 cur[4];
#pragma unroll
    for (int ct = 0; ct < 4; ++ct)
        cur[ct] = *(const bf16x8*)(bptr + ct * 512);       // step 0 fragments

    for (int ch = 0; ch < 32; ++ch) {
        const int kb = ch * 256;
        const unsigned short* bchp = bptr + ch * 65536;    // 8 steps x 8192 shorts
        f32x4 acc[4][4];
#pragma unroll
        for (int rt = 0; rt < 4; ++rt)
#pragma unroll
            for (int ct = 0; ct < 4; ++ct) acc[rt][ct] = (f32x4){0.f, 0.f, 0.f, 0.f};

#pragma unroll
        for (int cs = 0; cs < 8; ++cs) {
            // prefetch step s+1 fragments (2-deep reg pipeline, per-wave vmcnt)
            bf16x8 nxt[4];
            if (cs < 7 || ch < 31) {
                const unsigned short* np = bchp + (cs + 1) * 8192;
#pragma unroll
                for (int ct = 0; ct < 4; ++ct)
                    nxt[ct] = *(const bf16x8*)(np + ct * 512);
            } else {
#pragma unroll
                for (int ct = 0; ct < 4; ++ct) nxt[ct] = cur[ct];
            }
            // compute step s
#pragma unroll
            for (int rt = 0; rt < 4; ++rt) {
                const int as = (cs * 4 + q) * 64 + rt * 16 + nn;
                const bf16x8 ah = *(const bf16x8*)&As[as * 8];
#pragma unroll
                for (int ct = 0; ct < 4; ++ct)
                    acc[rt][ct] = __builtin_amdgcn_mfma_f32_16x16x32_bf16(ah, cur[ct], acc[rt][ct], 0, 0, 0);
            }
#pragma unroll
            for (int ct = 0; ct < 4; ++ct) cur[ct] = nxt[ct];
        }

        // ---- fold: approx d, shared row-max, candidate collection ----
        float wnv[4];
#pragma unroll
        for (int ct = 0; ct < 4; ++ct) wnv[ct] = wnH[kb + w * 64 + ct * 16 + nn];
        float rmax[16];
#pragma unroll
        for (int r16 = 0; r16 < 16; ++r16) rmax[r16] = -3.0e38f;
#pragma unroll
        for (int rt = 0; rt < 4; ++rt)
#pragma unroll
            for (int ct = 0; ct < 4; ++ct)
#pragma unroll
                for (int rg = 0; rg < 4; ++rg) {
                    const float dv = __builtin_fmaf(2.0f, acc[rt][ct][rg], -wnv[ct]);
                    rmax[rt * 4 + rg] = fmaxf(rmax[rt * 4 + rg], dv);
                }
#pragma unroll
        for (int r16 = 0; r16 < 16; ++r16) {
            float m = rmax[r16];
            m = fmaxf(m, __shfl_xor(m, 1, 64));
            m = fmaxf(m, __shfl_xor(m, 2, 64));
            m = fmaxf(m, __shfl_xor(m, 4, 64));
            m = fmaxf(m, __shfl_xor(m, 8, 64));
            rmax[r16] = m;
        }
        if (nn == 0) {
#pragma unroll
            for (int rt = 0; rt < 4; ++rt)
#pragma unroll
                for (int rg = 0; rg < 4; ++rg)
                    atomicMax(&rowmaxU[rt * 16 + q * 4 + rg], monof(rmax[rt * 4 + rg]));
        }
        __syncthreads();       // rowmax merged across waves
        float th[16];
#pragma unroll
        for (int rt = 0; rt < 4; ++rt)
#pragma unroll
            for (int rg = 0; rg < 4; ++rg)
                th[rt * 4 + rg] = unmonof(rowmaxU[rt * 16 + q * 4 + rg]) - MARGIN;
#pragma unroll
        for (int rt = 0; rt < 4; ++rt)
#pragma unroll
            for (int ct = 0; ct < 4; ++ct)
#pragma unroll
                for (int rg = 0; rg < 4; ++rg) {
                    const float dv = __builtin_fmaf(2.0f, acc[rt][ct][rg], -wnv[ct]);
                    if (dv >= th[rt * 4 + rg]) {
                        const int row = rt * 16 + q * 4 + rg;
                        const int pos = atomicAdd(&ccnt[row], 1);
                        if (pos < CAPH)
                            ck[row][pos] = (unsigned short)(half * KHALF + kb + w * 64 + ct * 16 + nn);
                    }
                }
        // no trailing barrier needed: a fast wave's ch+1 atomicMax can only RAISE
        // rowmaxU, and any threshold <= globalMax - MARGIN keeps the true argmax.
    }
    __syncthreads();
    if (tid < 64) candc[(rowBase + tid) * 2 + half] = ccnt[tid];
#pragma unroll
    for (int i = 0; i < 16; ++i) {
        const int e = i * 256 + tid;    // 4096 entries = 64 rows x CAPH(64)
        candk[((rowBase + (e >> 6)) * 2 + half) * CAPH + (e & 63)] = ck[e >> 6][e & 63];
    }
}

// ---------- K3: exact rescore — merge both K-halves' candidate lists ----------
__global__ __launch_bounds__(256) void k3_rescore(
    const float* __restrict__ xt, const float* __restrict__ weight,
    const float* __restrict__ wn, const float* __restrict__ ns1,
    const unsigned short* __restrict__ candk, const int* __restrict__ candc,
    int* __restrict__ idx)
{
    const int w = threadIdx.x >> 6, lane = threadIdx.x & 63;
    const int waveId = blockIdx.x * 4 + w;        // 0..4095
#pragma unroll
    for (int rr = 0; rr < 4; ++rr) {
        const int n = waveId * 4 + rr;
        const float4 xv = ((const float4*)(xt + n * 256))[lane];
        const float nsv = ns1[n];
        float bestd = -3.0e38f; int bestk = 0x7fffffff;
#pragma unroll
        for (int half = 0; half < 2; ++half) {
            const int cnt = candc[n * 2 + half];
            if (cnt <= CAPH) {
                for (int i = 0; i < cnt; ++i) {
                    const int k = candk[(n * 2 + half) * CAPH + i];
                    const float4 wv = ((const float4*)(weight + k * 256))[lane];
                    float p = __fmul_rn(xv.x, wv.x);
                    p = __builtin_fmaf(xv.y, wv.y, p);
                    p = __builtin_fmaf(xv.z, wv.z, p);
                    p = __builtin_fmaf(xv.w, wv.w, p);
#pragma unroll
                    for (int off = 1; off < 64; off <<= 1) p += __shfl_xor(p, off, 64);
                    const float t1 = __fadd_rn(nsv, -wn[k]);
                    const float dd = __fadd_rn(t1, __fmul_rn(2.0f, p));
                    if (dd > bestd || (dd == bestd && k < bestk)) { bestd = dd; bestk = k; }
                }
            } else {          // overflow fallback: exact scan of this half
                for (int k = half * KHALF; k < (half + 1) * KHALF; ++k) {
                    const float4 wv = ((const float4*)(weight + k * 256))[lane];
                    float p = __fmul_rn(xv.x, wv.x);
                    p = __builtin_fmaf(xv.y, wv.y, p);
                    p = __builtin_fmaf(xv.z, wv.z, p);
                    p = __builtin_fmaf(xv.w, wv.w, p);
#pragma unroll
                    for (int off = 1; off < 64; off <<= 1) p += __shfl_xor(p, off, 64);
                    const float t1 = __fadd_rn(nsv, -wn[k]);
                    const float dd = __fadd_rn(t1, __fmul_rn(2.0f, p));
                    if (dd > bestd || (dd == bestd && k < bestk)) { bestd = dd; bestk = k; }
                }
            }
        }
        if (lane == 0) idx[n] = bestk;
    }
}

// ---------- K5: gather + transpose-tile coalesced store + loss partials -------
__global__ void k5_out(const float* __restrict__ xt, const float* __restrict__ weight,
                       const float* __restrict__ mask, const int* __restrict__ idx,
                       float* __restrict__ out, float* __restrict__ part)
{
    __shared__ float t[32][33];
    __shared__ float red[4][2];
    const int p0 = blockIdx.x * 32, c0 = blockIdx.y * 32, b = blockIdx.z;
    const int tx = threadIdx.x, ty = threadIdx.y;
    float vloc = 0.f, mloc = 0.f;
#pragma unroll
    for (int i = 0; i < 4; ++i) {
        const int pl = ty + i * 8;
        const int n = b * 1024 + p0 + pl;
        const int id = idx[n];
        const float wq = weight[id * 256 + c0 + tx];      // coalesced 128B per row
        const float xv = xt[n * 256 + c0 + tx];           // coalesced
        const float mval = mask[b * 1024 + p0 + pl];      // broadcast
        t[tx][pl] = wq;                                   // t[c-local][p-local]
        const float e = wq - xv;
        vloc += mval * e * e;
        if (blockIdx.y == 0 && tx == 0) {
            mloc += mval;
            out[OUT_IND + n] = (float)id;
        }
    }
    __syncthreads();
#pragma unroll
    for (int i = 0; i < 4; ++i) {
        const int cl = ty + i * 8;
        out[(b * 256 + c0 + cl) * 1024 + p0 + tx] = t[cl][tx];   // coalesced in tx
    }
    const int lin = ty * 32 + tx, lane = lin & 63, w = lin >> 6;
#pragma unroll
    for (int o = 32; o > 0; o >>= 1) {
        vloc += __shfl_down(vloc, o, 64);
        mloc += __shfl_down(mloc, o, 64);
    }
    if (lane == 0) { red[w][0] = mloc; red[w][1] = vloc; }
    __syncthreads();
    if (lin == 0) {
        const int bid = (b * 8 + blockIdx.y) * 32 + blockIdx.x;
        part[bid * 2 + 0] = red[0][0] + red[1][0] + red[2][0] + red[3][0];
        part[bid * 2 + 1] = red[0][1] + red[1][1] + red[2][1] + red[3][1];
    }
}

// ---------- K6: deterministic tree-reduce of 4096 partials + finalize loss ----
__global__ void k6_final(const float* __restrict__ part, float* __restrict__ out)
{
    __shared__ double red[4][2];
    const int tid = threadIdx.x;
    double m = 0.0, s = 0.0;
    for (int i = tid; i < 4096; i += 256) {
        m += (double)part[i * 2 + 0];
        s += (double)part[i * 2 + 1];
    }
    const int lane = tid & 63, w = tid >> 6;
    for (int o = 32; o > 0; o >>= 1) {
        m += __shfl_down(m, o, 64);
        s += __shfl_down(s, o, 64);
    }
    if (lane == 0) { red[w][0] = m; red[w][1] = s; }
    __syncthreads();
    if (tid == 0) {
        const double mt = red[0][0] + red[1][0] + red[2][0] + red[3][0];
        const double st = red[0][1] + red[1][1] + red[2][1] + red[3][1];
        out[OUT_LOSS] = (float)(1.25 * st / (256.0 * mt));
    }
}

extern "C" void kernel_launch(void* const* d_in, const int* in_sizes, int n_in,
                              void* d_out, int out_size, void* d_ws, size_t ws_size,
                              hipStream_t stream)
{
    const float* x      = (const float*)d_in[0];   // [16,256,32,32]
    const float* mask   = (const float*)d_in[1];   // [16,1,32,32]
    const float* weight = (const float*)d_in[2];   // [16384,256]
    float* out = (float*)d_out;
    float* ws  = (float*)d_ws;

    float* xt  = ws + OFF_XT;
    unsigned short* xhp = (unsigned short*)(ws + OFF_XHP);
    unsigned short* whp = (unsigned short*)(ws + OFF_WHP);
    float* wn   = ws + OFF_WN;
    float* ns1  = ws + OFF_NS1;
    int*   idx  = (int*)(ws + OFF_IDX);
    unsigned short* candk = (unsigned short*)(ws + OFF_CAND);
    int*   candc = (int*)(ws + OFF_CCNT);
    float* part = ws + OFF_PART;

    k1a_pack_x<<<dim3(32, 8, 16), dim3(32, 8), 0, stream>>>(x, xt, xhp);
    k_rownorm<<<512, 256, 0, stream>>>((const float4*)xt, ns1, -1.0f, nullptr);
    k_rownorm<<<512, 256, 0, stream>>>((const float4*)weight, wn, 1.0f, whp);
    k2_mfma<<<512, 256, 0, stream>>>(xhp, whp, wn, candk, candc);
    k3_rescore<<<1024, 256, 0, stream>>>(xt, weight, wn, ns1, candk, candc, idx);
    k5_out<<<dim3(32, 8, 16), dim3(32, 8), 0, stream>>>(xt, weight, mask, idx, out, part);
    k6_final<<<1, 256, 0, stream>>>(part, out);
}

// Round 5
// 371.764 us; speedup vs baseline: 1.1984x; 1.0411x over previous
//
#include <hip/hip_runtime.h>

// Problem: B,C,H,W = 16,256,32,32; K=16384. N = 16384 rows.
// R15: R4 post-mortem: barrier-free direct-B loop works (252us) but is latency-
//      stalled: MfmaUtil+VALUBusy ~50%, occupancy grid-capped at 2 waves/SIMD
//      (512 blocks = 2/CU). Fix: K-split-4 -- 64 rows x 2MB codebook QUARTER per
//      block, 1024 blocks = 4 blocks/CU = 4 waves/SIMD (2x TLP), SAME total
//      traffic (1024 x 2MB = 2.15GB). With quarter = bid&3 and XCD = bid%8,
//      XCD j only touches quarter j&3 -> 2MB working set fully L2-resident per
//      XCD; steady-state B-reads are ~200cyc L2 hits inside the ~300cyc TLP
//      window. Candidates per-(row, quarter), CAPH_Q=32 (E[count]~1.6 over a
//      4096-code quarter; fallback scan kept). LDS 36.6KB x 4 = 146KB/CU.
#define KCODES 16384
#define NPOS   16384
#define KQUART 4096
#define CAPH   32      // per-quarter candidate cap
#define MARGIN 1e-4f   // ~5x the bf16-input dot error (~2e-5 worst) on d

// ws float offsets (all within the 52.7MB footprint proven in R0)
#define OFF_XT    0           // [N][256] fp32 packed x ("flat")
#define OFF_XHP   4194304     // bf16 plane xh [N][256] (linear)
#define OFF_PART  6291456     // [4096][2] k5 per-block {mask,err} partials
#define OFF_CAND  6815744     // u16 [N][4][CAPH] candidate codes (1M floats)
#define OFF_WHP   8388608     // bf16 plane wh, SWIZZLED [quarter][s][w][ct][nn][q][8]
#define OFF_WN    12582912    // [K]  |w|^2 (np-pairwise exact)
#define OFF_NS1   12599296    // [N] -|f|^2
#define OFF_IDX   12615680    // [N] final argmax (int)
#define OFF_CCNT  12632064    // int [N][4] candidate counts

#define OUT_LOSS  4194304
#define OUT_IND   4194305

#define AS1 __attribute__((address_space(1)))
#define AS3 __attribute__((address_space(3)))

typedef short bf16x8 __attribute__((ext_vector_type(8)));   // 8 bf16 = 4 VGPRs
typedef float f32x4  __attribute__((ext_vector_type(4)));

__device__ inline unsigned short bf16rn(float f) {
    unsigned u = __float_as_uint(f);
    return (unsigned short)((u + 0x7FFFu + ((u >> 16) & 1u)) >> 16);
}
__device__ inline float bf2f(unsigned short h) {
    return __uint_as_float(((unsigned)h) << 16);
}
__device__ inline unsigned monof(float f) {   // monotone float->uint key
    unsigned u = __float_as_uint(f);
    return (u & 0x80000000u) ? ~u : (u | 0x80000000u);
}
__device__ inline float unmonof(unsigned k) {
    unsigned u = (k & 0x80000000u) ? (k & 0x7fffffffu) : ~k;
    return __uint_as_float(u);
}

// ---------- K1a: pack x (B,C,HW) -> xt[N][256] fp32 + xh bf16, LDS transpose ----
__global__ void k1a_pack_x(const float* __restrict__ x, float* __restrict__ xt,
                           unsigned short* __restrict__ xhp)
{
    __shared__ float t[32][33];
    const int p0 = blockIdx.x * 32, c0 = blockIdx.y * 32, b = blockIdx.z;
    const int tx = threadIdx.x, ty = threadIdx.y;   // 32 x 8
#pragma unroll
    for (int i = 0; i < 4; ++i) {
        int cl = ty + i * 8;
        t[cl][tx] = x[(b * 256 + c0 + cl) * 1024 + p0 + tx];
    }
    __syncthreads();
#pragma unroll
    for (int i = 0; i < 4; ++i) {
        int pl = ty + i * 8;
        float v = t[tx][pl];
        int o = (b * 1024 + p0 + pl) * 256 + c0 + tx;
        xt[o] = v;
        xhp[o] = bf16rn(v);
    }
}

// ---------- Krn: numpy-pairwise fp32 row |.|^2; weight path also emits the ------
// ---------- SWIZZLED bf16 plane in k2's fragment order -------------------------
// swizzle: code k -> (qt = k>>12; chi = (k&4095)>>8; rem = k&255 -> w,ct,nn),
// channel c (as float4 idx c4 = c/4) -> (cs = c4>>3; q = (c4>>1)&3; e4 = c4&1).
// short idx = qt*1048576 + (chi*8+cs)*8192 + w*2048 + ct*512 + nn*32 + q*8 + e4*4.
__global__ void k_rownorm(const float4* __restrict__ src4, float* __restrict__ out,
                          float sign, unsigned short* __restrict__ hp_swz)
{
    __shared__ float4 rows[32 * 64];
    const int tid = threadIdx.x;
    const int r0 = blockIdx.x * 32;
#pragma unroll
    for (int i = 0; i < 8; ++i) {
        const int F = r0 * 64 + tid + 256 * i;    // float4 index: row = F>>6, c4 = F&63
        const float4 v = src4[F];
        rows[tid + 256 * i] = v;
        if (hp_swz) {
            ushort4 h;
            h.x = bf16rn(v.x); h.y = bf16rn(v.y);
            h.z = bf16rn(v.z); h.w = bf16rn(v.w);
            const int row = F >> 6, c4 = F & 63;
            const int qt = row >> 12, kk = row & 4095;
            const int chi = kk >> 8, rem = kk & 255;
            const int wq = rem >> 6, ct = (rem >> 4) & 3, n4 = rem & 15;
            const int cs = c4 >> 3, qq = (c4 >> 1) & 3, e4 = c4 & 1;
            const int sidx = qt * 1048576 + (chi * 8 + cs) * 8192
                           + wq * 2048 + ct * 512 + n4 * 32 + qq * 8 + e4 * 4;
            *(ushort4*)(hp_swz + sidx) = h;
        }
    }
    __syncthreads();
    const int rl = tid >> 3, j = tid & 7;
    const float* qp = (const float*)&rows[rl * 64];
    float h[2];
#pragma unroll
    for (int half = 0; half < 2; ++half) {
        const float* p = qp + half * 128;
        float x = p[j];
        float r = __fmul_rn(x, x);
#pragma unroll
        for (int i = 1; i < 16; ++i) {
            float y = p[8 * i + j];
            r = __fadd_rn(r, __fmul_rn(y, y));
        }
        float t = __fadd_rn(r, __shfl_xor(r, 1));
        t = __fadd_rn(t, __shfl_xor(t, 2));
        t = __fadd_rn(t, __shfl_xor(t, 4));
        h[half] = t;
    }
    if (j == 0) out[r0 + rl] = sign * __fadd_rn(h[0], h[1]);
}

// ---------- K2: 64-row x K-quarter, direct-to-reg B loads, barrier-free loop ---
// d_approx = 2*(xh.wh) - |w|^2 (per-row -|f|^2 constant omitted: argmax-invariant).
// Block = (rowGroup = bid>>2) x (quarter = bid&3). 1024 blocks = 4/CU, 4 waves/SIMD.
__global__ __launch_bounds__(256, 4) void k2_mfma(
    const unsigned short* __restrict__ xhp, const unsigned short* __restrict__ whp,
    const float* __restrict__ wn,
    unsigned short* __restrict__ candk, int* __restrict__ candc)
{
    __shared__ __align__(16) unsigned short As[16384];     // 32KB: slot16 = cc*64 + row
    __shared__ unsigned rowmaxU[64];
    __shared__ int ccnt[64];
    __shared__ unsigned short ck[64][CAPH];                // 4 KB

    const int tid  = threadIdx.x;
    const int lane = tid & 63;
    const int w    = tid >> 6;     // wave 0..3 -> code sub-range
    const int q    = lane >> 4;    // k-chunk quad
    const int nn   = lane & 15;    // A-row / B-col / D-col position
    const int qt   = blockIdx.x & 3;
    const int rowBase = (blockIdx.x >> 2) * 64;
    const unsigned short* whpQ = whp + qt * 1048576;
    const float* wnQ = wn + qt * KQUART;

    // stage A once: 1024 slots of 16B (64 rows x 256 ch bf16), linear dest
#pragma unroll
    for (int i = 0; i < 8; ++i) {
        const int slot = i * 256 + tid;
        const int cc = slot >> 6, row = slot & 63;
        const unsigned short* src = xhp + (rowBase + row) * 256 + cc * 8;
        __builtin_amdgcn_global_load_lds((const AS1 void*)src,
                                         (AS3 void*)((char*)&As[0] + slot * 16), 16, 0, 0);
    }
    if (tid < 64) { rowmaxU[tid] = 0u; ccnt[tid] = 0; }

    // per-lane fragment pointer into the swizzled codebook quarter
    const unsigned short* bptr = whpQ + (w * 2048 + nn * 32 + q * 8);

    __syncthreads();           // As staged (drains vmcnt once, prologue only)

    bf16x8 cur[4];
#pragma unroll
    for (int ct = 0; ct < 4; ++ct)
        cur[ct] = *(const bf16x8*)(bptr + ct * 512);       // step 0 fragments

    for (int ch = 0; ch < 16; ++ch) {
        const int kb = ch * 256;
        const unsigned short* bchp = bptr + ch * 65536;    // 8 steps x 8192 shorts
        f32x4 acc[4][4];
#pragma unroll
        for (int rt = 0; rt < 4; ++rt)
#pragma unroll
            for (int ct = 0; ct < 4; ++ct) acc[rt][ct] = (f32x4){0.f, 0.f, 0.f, 0.f};

#pragma unroll
        for (int cs = 0; cs < 8; ++cs) {
            // prefetch step s+1 fragments (2-deep reg pipeline, per-wave vmcnt;
            // contiguous layout makes bchp+8*8192 == next ch's step 0)
            bf16x8 nxt[4];
            if (cs < 7 || ch < 15) {
                const unsigned short* np = bchp + (cs + 1) * 8192;
#pragma unroll
                for (int ct = 0; ct < 4; ++ct)
                    nxt[ct] = *(const bf16x8*)(np + ct * 512);
            } else {
#pragma unroll
                for (int ct = 0; ct < 4; ++ct) nxt[ct] = cur[ct];
            }
            // compute step s
#pragma unroll
            for (int rt = 0; rt < 4; ++rt) {
                const int as = (cs * 4 + q) * 64 + rt * 16 + nn;
                const bf16x8 ah = *(const bf16x8*)&As[as * 8];
#pragma unroll
                for (int ct = 0; ct < 4; ++ct)
                    acc[rt][ct] = __builtin_amdgcn_mfma_f32_16x16x32_bf16(ah, cur[ct], acc[rt][ct], 0, 0, 0);
            }
#pragma unroll
            for (int ct = 0; ct < 4; ++ct) cur[ct] = nxt[ct];
        }

        // ---- fold: approx d, shared row-max, candidate collection ----
        float wnv[4];
#pragma unroll
        for (int ct = 0; ct < 4; ++ct) wnv[ct] = wnQ[kb + w * 64 + ct * 16 + nn];
        float rmax[16];
#pragma unroll
        for (int r16 = 0; r16 < 16; ++r16) rmax[r16] = -3.0e38f;
#pragma unroll
        for (int rt = 0; rt < 4; ++rt)
#pragma unroll
            for (int ct = 0; ct < 4; ++ct)
#pragma unroll
                for (int rg = 0; rg < 4; ++rg) {
                    const float dv = __builtin_fmaf(2.0f, acc[rt][ct][rg], -wnv[ct]);
                    rmax[rt * 4 + rg] = fmaxf(rmax[rt * 4 + rg], dv);
                }
#pragma unroll
        for (int r16 = 0; r16 < 16; ++r16) {
            float m = rmax[r16];
            m = fmaxf(m, __shfl_xor(m, 1, 64));
            m = fmaxf(m, __shfl_xor(m, 2, 64));
            m = fmaxf(m, __shfl_xor(m, 4, 64));
            m = fmaxf(m, __shfl_xor(m, 8, 64));
            rmax[r16] = m;
        }
        if (nn == 0) {
#pragma unroll
            for (int rt = 0; rt < 4; ++rt)
#pragma unroll
                for (int rg = 0; rg < 4; ++rg)
                    atomicMax(&rowmaxU[rt * 16 + q * 4 + rg], monof(rmax[rt * 4 + rg]));
        }
        __syncthreads();       // rowmax merged across waves
        float th[16];
#pragma unroll
        for (int rt = 0; rt < 4; ++rt)
#pragma unroll
            for (int rg = 0; rg < 4; ++rg)
                th[rt * 4 + rg] = unmonof(rowmaxU[rt * 16 + q * 4 + rg]) - MARGIN;
#pragma unroll
        for (int rt = 0; rt < 4; ++rt)
#pragma unroll
            for (int ct = 0; ct < 4; ++ct)
#pragma unroll
                for (int rg = 0; rg < 4; ++rg) {
                    const float dv = __builtin_fmaf(2.0f, acc[rt][ct][rg], -wnv[ct]);
                    if (dv >= th[rt * 4 + rg]) {
                        const int row = rt * 16 + q * 4 + rg;
                        const int pos = atomicAdd(&ccnt[row], 1);
                        if (pos < CAPH)
                            ck[row][pos] = (unsigned short)(qt * KQUART + kb + w * 64 + ct * 16 + nn);
                    }
                }
        // no trailing barrier needed: a fast wave's ch+1 atomicMax can only RAISE
        // rowmaxU, and any threshold <= quarterMax - MARGIN keeps the true argmax.
    }
    __syncthreads();
    if (tid < 64) candc[(rowBase + tid) * 4 + qt] = ccnt[tid];
#pragma unroll
    for (int i = 0; i < 8; ++i) {
        const int e = i * 256 + tid;    // 2048 entries = 64 rows x CAPH(32)
        candk[((rowBase + (e >> 5)) * 4 + qt) * CAPH + (e & 31)] = ck[e >> 5][e & 31];
    }
}

// ---------- K3: exact rescore — merge all four quarters' candidate lists -------
__global__ __launch_bounds__(256) void k3_rescore(
    const float* __restrict__ xt, const float* __restrict__ weight,
    const float* __restrict__ wn, const float* __restrict__ ns1,
    const unsigned short* __restrict__ candk, const int* __restrict__ candc,
    int* __restrict__ idx)
{
    const int w = threadIdx.x >> 6, lane = threadIdx.x & 63;
    const int waveId = blockIdx.x * 4 + w;        // 0..4095
#pragma unroll
    for (int rr = 0; rr < 4; ++rr) {
        const int n = waveId * 4 + rr;
        const float4 xv = ((const float4*)(xt + n * 256))[lane];
        const float nsv = ns1[n];
        float bestd = -3.0e38f; int bestk = 0x7fffffff;
#pragma unroll
        for (int qt = 0; qt < 4; ++qt) {
            const int cnt = candc[n * 4 + qt];
            if (cnt <= CAPH) {
                for (int i = 0; i < cnt; ++i) {
                    const int k = candk[(n * 4 + qt) * CAPH + i];
                    const float4 wv = ((const float4*)(weight + k * 256))[lane];
                    float p = __fmul_rn(xv.x, wv.x);
                    p = __builtin_fmaf(xv.y, wv.y, p);
                    p = __builtin_fmaf(xv.z, wv.z, p);
                    p = __builtin_fmaf(xv.w, wv.w, p);
#pragma unroll
                    for (int off = 1; off < 64; off <<= 1) p += __shfl_xor(p, off, 64);
                    const float t1 = __fadd_rn(nsv, -wn[k]);
                    const float dd = __fadd_rn(t1, __fmul_rn(2.0f, p));
                    if (dd > bestd || (dd == bestd && k < bestk)) { bestd = dd; bestk = k; }
                }
            } else {          // overflow fallback: exact scan of this quarter
                for (int k = qt * KQUART; k < (qt + 1) * KQUART; ++k) {
                    const float4 wv = ((const float4*)(weight + k * 256))[lane];
                    float p = __fmul_rn(xv.x, wv.x);
                    p = __builtin_fmaf(xv.y, wv.y, p);
                    p = __builtin_fmaf(xv.z, wv.z, p);
                    p = __builtin_fmaf(xv.w, wv.w, p);
#pragma unroll
                    for (int off = 1; off < 64; off <<= 1) p += __shfl_xor(p, off, 64);
                    const float t1 = __fadd_rn(nsv, -wn[k]);
                    const float dd = __fadd_rn(t1, __fmul_rn(2.0f, p));
                    if (dd > bestd || (dd == bestd && k < bestk)) { bestd = dd; bestk = k; }
                }
            }
        }
        if (lane == 0) idx[n] = bestk;
    }
}

// ---------- K5: gather + transpose-tile coalesced store + loss partials -------
__global__ void k5_out(const float* __restrict__ xt, const float* __restrict__ weight,
                       const float* __restrict__ mask, const int* __restrict__ idx,
                       float* __restrict__ out, float* __restrict__ part)
{
    __shared__ float t[32][33];
    __shared__ float red[4][2];
    const int p0 = blockIdx.x * 32, c0 = blockIdx.y * 32, b = blockIdx.z;
    const int tx = threadIdx.x, ty = threadIdx.y;
    float vloc = 0.f, mloc = 0.f;
#pragma unroll
    for (int i = 0; i < 4; ++i) {
        const int pl = ty + i * 8;
        const int n = b * 1024 + p0 + pl;
        const int id = idx[n];
        const float wq = weight[id * 256 + c0 + tx];      // coalesced 128B per row
        const float xv = xt[n * 256 + c0 + tx];           // coalesced
        const float mval = mask[b * 1024 + p0 + pl];      // broadcast
        t[tx][pl] = wq;                                   // t[c-local][p-local]
        const float e = wq - xv;
        vloc += mval * e * e;
        if (blockIdx.y == 0 && tx == 0) {
            mloc += mval;
            out[OUT_IND + n] = (float)id;
        }
    }
    __syncthreads();
#pragma unroll
    for (int i = 0; i < 4; ++i) {
        const int cl = ty + i * 8;
        out[(b * 256 + c0 + cl) * 1024 + p0 + tx] = t[cl][tx];   // coalesced in tx
    }
    const int lin = ty * 32 + tx, lane = lin & 63, w = lin >> 6;
#pragma unroll
    for (int o = 32; o > 0; o >>= 1) {
        vloc += __shfl_down(vloc, o, 64);
        mloc += __shfl_down(mloc, o, 64);
    }
    if (lane == 0) { red[w][0] = mloc; red[w][1] = vloc; }
    __syncthreads();
    if (lin == 0) {
        const int bid = (b * 8 + blockIdx.y) * 32 + blockIdx.x;
        part[bid * 2 + 0] = red[0][0] + red[1][0] + red[2][0] + red[3][0];
        part[bid * 2 + 1] = red[0][1] + red[1][1] + red[2][1] + red[3][1];
    }
}

// ---------- K6: deterministic tree-reduce of 4096 partials + finalize loss ----
__global__ void k6_final(const float* __restrict__ part, float* __restrict__ out)
{
    __shared__ double red[4][2];
    const int tid = threadIdx.x;
    double m = 0.0, s = 0.0;
    for (int i = tid; i < 4096; i += 256) {
        m += (double)part[i * 2 + 0];
        s += (double)part[i * 2 + 1];
    }
    const int lane = tid & 63, w = tid >> 6;
    for (int o = 32; o > 0; o >>= 1) {
        m += __shfl_down(m, o, 64);
        s += __shfl_down(s, o, 64);
    }
    if (lane == 0) { red[w][0] = m; red[w][1] = s; }
    __syncthreads();
    if (tid == 0) {
        const double mt = red[0][0] + red[1][0] + red[2][0] + red[3][0];
        const double st = red[0][1] + red[1][1] + red[2][1] + red[3][1];
        out[OUT_LOSS] = (float)(1.25 * st / (256.0 * mt));
    }
}

extern "C" void kernel_launch(void* const* d_in, const int* in_sizes, int n_in,
                              void* d_out, int out_size, void* d_ws, size_t ws_size,
                              hipStream_t stream)
{
    const float* x      = (const float*)d_in[0];   // [16,256,32,32]
    const float* mask   = (const float*)d_in[1];   // [16,1,32,32]
    const float* weight = (const float*)d_in[2];   // [16384,256]
    float* out = (float*)d_out;
    float* ws  = (float*)d_ws;

    float* xt  = ws + OFF_XT;
    unsigned short* xhp = (unsigned short*)(ws + OFF_XHP);
    unsigned short* whp = (unsigned short*)(ws + OFF_WHP);
    float* wn   = ws + OFF_WN;
    float* ns1  = ws + OFF_NS1;
    int*   idx  = (int*)(ws + OFF_IDX);
    unsigned short* candk = (unsigned short*)(ws + OFF_CAND);
    int*   candc = (int*)(ws + OFF_CCNT);
    float* part = ws + OFF_PART;

    k1a_pack_x<<<dim3(32, 8, 16), dim3(32, 8), 0, stream>>>(x, xt, xhp);
    k_rownorm<<<512, 256, 0, stream>>>((const float4*)xt, ns1, -1.0f, nullptr);
    k_rownorm<<<512, 256, 0, stream>>>((const float4*)weight, wn, 1.0f, whp);
    k2_mfma<<<1024, 256, 0, stream>>>(xhp, whp, wn, candk, candc);
    k3_rescore<<<1024, 256, 0, stream>>>(xt, weight, wn, ns1, candk, candc, idx);
    k5_out<<<dim3(32, 8, 16), dim3(32, 8), 0, stream>>>(xt, weight, mask, idx, out, part);
    k6_final<<<1, 256, 0, stream>>>(part, out);
}